// Round 1
// baseline (523.962 us; speedup 1.0000x reference)
//
#include <hip/hip_runtime.h>

// SGConvolution: h = A @ (A @ x), A sparse COO (row sorted), N=100000, E=1600000, D=64.
//
// Strategy R0: one 64-lane wave owns a contiguous chunk of EPW edges; lane d
// owns feature dim d (D == wave width == 64). Because edge_row is sorted,
// consecutive edges in a chunk mostly share the same destination row, so each
// lane accumulates val*h[col*64+lane] in a register and only does an
// atomicAdd(out[row*64+lane]) when the row changes (avg degree 16 -> ~16x
// fewer atomics than per-edge).

#define N_NODES 100000
#define N_EDGES 1600000
#define D_FEAT  64
#define EPW     256   // edges per wave

__global__ __launch_bounds__(256) void sg_spmm_kernel(
    const float* __restrict__ h,          // [N, 64] input features
    const int*   __restrict__ erow,       // [E] sorted destination rows
    const int*   __restrict__ ecol,       // [E] source cols
    const float* __restrict__ eval,       // [E] edge weights
    float*       __restrict__ out)        // [N, 64] pre-zeroed output
{
    const int lane = threadIdx.x & 63;
    const long wave = (long)((blockIdx.x * (long)blockDim.x + threadIdx.x) >> 6);
    long start = wave * (long)EPW;
    if (start >= N_EDGES) return;
    long end = start + EPW;
    if (end > N_EDGES) end = N_EDGES;

    int cur_row = erow[start];
    float acc = 0.0f;

    for (long e = start; e < end; ++e) {
        int r = erow[e];
        if (r != cur_row) {
            atomicAdd(&out[(long)cur_row * D_FEAT + lane], acc);
            acc = 0.0f;
            cur_row = r;
        }
        int   c = ecol[e];
        float v = eval[e];
        acc += v * h[(long)c * D_FEAT + lane];
    }
    atomicAdd(&out[(long)cur_row * D_FEAT + lane], acc);
}

extern "C" void kernel_launch(void* const* d_in, const int* in_sizes, int n_in,
                              void* d_out, int out_size, void* d_ws, size_t ws_size,
                              hipStream_t stream) {
    const float* x    = (const float*)d_in[0];
    const int*   erow = (const int*)  d_in[1];
    const int*   ecol = (const int*)  d_in[2];
    const float* eval = (const float*)d_in[3];
    float*       out  = (float*)d_out;
    float*       h1   = (float*)d_ws;   // intermediate [N, 64] = 25.6 MB

    const size_t feat_bytes = (size_t)N_NODES * D_FEAT * sizeof(float);

    const int waves  = (N_EDGES + EPW - 1) / EPW;         // 6250
    const int threads = 256;                               // 4 waves/block
    const int blocks = (waves * 64 + threads - 1) / threads;

    // ws and out are poisoned 0xAA before every timed call — zero them.
    hipMemsetAsync(h1, 0, feat_bytes, stream);
    hipMemsetAsync(out, 0, feat_bytes, stream);

    // Round 1: h1 = A @ x
    sg_spmm_kernel<<<blocks, threads, 0, stream>>>(x, erow, ecol, eval, h1);
    // Round 2: out = A @ h1
    sg_spmm_kernel<<<blocks, threads, 0, stream>>>(h1, erow, ecol, eval, out);
}

// Round 2
// 223.023 us; speedup vs baseline: 2.3494x; 2.3494x over previous
//
#include <hip/hip_runtime.h>

// SGConvolution: out = A @ (A @ x), A sparse COO (edge_row sorted).
// N=100000, E=1600000, D=64 (== wave width; lane d owns feature d).
//
// R1 -> R2: latency-bound fix. Unroll 8 edges per step (8 independent
// gathers in flight) and halve EPW (128) to double wave-level parallelism.
// Register accumulation with boundary-flush atomics (rows sorted).

#define N_NODES 100000
#define N_EDGES 1600000
#define D_FEAT  64
#define EPW     128   // edges per wave; 1600000 / 128 = 12500 waves exactly
#define U       8     // unroll: independent gathers in flight per wave

__global__ __launch_bounds__(256) void sg_spmm_kernel(
    const float* __restrict__ h,          // [N, 64] input features
    const int*   __restrict__ erow,       // [E] sorted destination rows
    const int*   __restrict__ ecol,       // [E] source cols
    const float* __restrict__ eval,       // [E] edge weights
    float*       __restrict__ out)        // [N, 64] pre-zeroed output
{
    const int lane = threadIdx.x & 63;
    const int wave = (int)((blockIdx.x * blockDim.x + threadIdx.x) >> 6);
    const int start = wave * EPW;
    if (start >= N_EDGES) return;

    int cur_row = erow[start];
    float acc = 0.0f;

    // EPW divides N_EDGES exactly -> no tail handling.
    for (int e = start; e < start + EPW; e += U) {
        int r[U], c[U];
        float v[U];
#pragma unroll
        for (int j = 0; j < U; ++j) {
            r[j] = erow[e + j];
            c[j] = ecol[e + j];
            v[j] = eval[e + j];
        }
        float g[U];
#pragma unroll
        for (int j = 0; j < U; ++j) {
            g[j] = h[(size_t)c[j] * D_FEAT + lane];   // 8 independent gathers
        }
#pragma unroll
        for (int j = 0; j < U; ++j) {
            if (r[j] != cur_row) {
                atomicAdd(&out[(size_t)cur_row * D_FEAT + lane], acc);
                acc = 0.0f;
                cur_row = r[j];
            }
            acc += v[j] * g[j];
        }
    }
    atomicAdd(&out[(size_t)cur_row * D_FEAT + lane], acc);
}

extern "C" void kernel_launch(void* const* d_in, const int* in_sizes, int n_in,
                              void* d_out, int out_size, void* d_ws, size_t ws_size,
                              hipStream_t stream) {
    const float* x    = (const float*)d_in[0];
    const int*   erow = (const int*)  d_in[1];
    const int*   ecol = (const int*)  d_in[2];
    const float* eval = (const float*)d_in[3];
    float*       out  = (float*)d_out;
    float*       h1   = (float*)d_ws;   // intermediate [N, 64] = 25.6 MB

    const size_t feat_bytes = (size_t)N_NODES * D_FEAT * sizeof(float);

    const int waves   = (N_EDGES + EPW - 1) / EPW;        // 12500
    const int threads = 256;                               // 4 waves/block
    const int blocks  = (waves * 64 + threads - 1) / threads;

    // ws and out are poisoned 0xAA before every timed call — zero them.
    hipMemsetAsync(h1, 0, feat_bytes, stream);
    hipMemsetAsync(out, 0, feat_bytes, stream);

    // Round 1: h1 = A @ x
    sg_spmm_kernel<<<blocks, threads, 0, stream>>>(x, erow, ecol, eval, h1);
    // Round 2: out = A @ h1
    sg_spmm_kernel<<<blocks, threads, 0, stream>>>(h1, erow, ecol, eval, out);
}

// Round 3
// 209.093 us; speedup vs baseline: 2.5059x; 1.0666x over previous
//
#include <hip/hip_runtime.h>

// SGConvolution: out = A @ (A @ x), A sparse COO (edge_row sorted).
// N=100000, E=1600000, D=64 (== wave width; lane d owns feature d).
//
// R2 -> R3: latency-bound fix #2.
//  - Edge triples (r,c,v) preloaded with coalesced per-lane loads (6 vector
//    loads per 128 edges) and broadcast via readlane -> SGPRs. Row-boundary
//    compare/flush becomes a scalar branch; gather address is SGPR base +
//    lane*4. The vmcnt queue now holds ONLY feature gathers.
//  - Gathers batched 64-deep into registers before the fold pass: ~64 loads
//    in flight per wave (16 KB) vs 8 before.

#define N_NODES 100000
#define N_EDGES 1600000
#define D_FEAT  64
#define EPW     128   // edges per wave; 1600000 / 128 = 12500 waves exactly

__device__ __forceinline__ float readlane_f(float x, int j) {
    return __uint_as_float(__builtin_amdgcn_readlane(__float_as_uint(x), j));
}

__global__ __launch_bounds__(256) void sg_spmm_kernel(
    const float* __restrict__ h,          // [N, 64] input features
    const int*   __restrict__ erow,       // [E] sorted destination rows
    const int*   __restrict__ ecol,       // [E] source cols
    const float* __restrict__ eval,       // [E] edge weights
    float*       __restrict__ out)        // [N, 64] pre-zeroed output
{
    const int lane  = threadIdx.x & 63;
    const int wave  = (int)((blockIdx.x * blockDim.x + threadIdx.x) >> 6);
    const int start = wave * EPW;
    if (start >= N_EDGES) return;

    // Coalesced preload of this wave's 128 edge triples (lane i holds edge
    // start+i and start+64+i).
    const int   r0 = erow[start + lane];
    const int   r1 = erow[start + 64 + lane];
    const int   c0 = ecol[start + lane];
    const int   c1 = ecol[start + 64 + lane];
    const float w0 = eval[start + lane];
    const float w1 = eval[start + 64 + lane];

    int   cur_row = __builtin_amdgcn_readlane(r0, 0);
    float acc     = 0.0f;

    float g[64];

    // ---- batch 0: edges [start, start+64) ----
#pragma unroll
    for (int j = 0; j < 64; ++j) {
        const int c = __builtin_amdgcn_readlane(c0, j);   // SGPR col
        g[j] = h[(size_t)c * D_FEAT + lane];              // independent gathers
    }
#pragma unroll
    for (int j = 0; j < 64; ++j) {
        const int r = __builtin_amdgcn_readlane(r0, j);   // SGPR row (sorted)
        if (r != cur_row) {                               // scalar branch
            atomicAdd(&out[(size_t)cur_row * D_FEAT + lane], acc);
            acc = 0.0f;
            cur_row = r;
        }
        acc += readlane_f(w0, j) * g[j];
    }

    // ---- batch 1: edges [start+64, start+128) ----
#pragma unroll
    for (int j = 0; j < 64; ++j) {
        const int c = __builtin_amdgcn_readlane(c1, j);
        g[j] = h[(size_t)c * D_FEAT + lane];
    }
#pragma unroll
    for (int j = 0; j < 64; ++j) {
        const int r = __builtin_amdgcn_readlane(r1, j);
        if (r != cur_row) {
            atomicAdd(&out[(size_t)cur_row * D_FEAT + lane], acc);
            acc = 0.0f;
            cur_row = r;
        }
        acc += readlane_f(w1, j) * g[j];
    }

    atomicAdd(&out[(size_t)cur_row * D_FEAT + lane], acc);
}

extern "C" void kernel_launch(void* const* d_in, const int* in_sizes, int n_in,
                              void* d_out, int out_size, void* d_ws, size_t ws_size,
                              hipStream_t stream) {
    const float* x    = (const float*)d_in[0];
    const int*   erow = (const int*)  d_in[1];
    const int*   ecol = (const int*)  d_in[2];
    const float* eval = (const float*)d_in[3];
    float*       out  = (float*)d_out;
    float*       h1   = (float*)d_ws;   // intermediate [N, 64] = 25.6 MB

    const size_t feat_bytes = (size_t)N_NODES * D_FEAT * sizeof(float);

    const int waves   = (N_EDGES + EPW - 1) / EPW;        // 12500
    const int threads = 256;                               // 4 waves/block
    const int blocks  = (waves * 64 + threads - 1) / threads;

    // ws and out are poisoned 0xAA before every timed call — zero them.
    hipMemsetAsync(h1, 0, feat_bytes, stream);
    hipMemsetAsync(out, 0, feat_bytes, stream);

    // Round 1: h1 = A @ x
    sg_spmm_kernel<<<blocks, threads, 0, stream>>>(x, erow, ecol, eval, h1);
    // Round 2: out = A @ h1
    sg_spmm_kernel<<<blocks, threads, 0, stream>>>(h1, erow, ecol, eval, out);
}

// Round 4
// 169.984 us; speedup vs baseline: 3.0824x; 1.2301x over previous
//
#include <hip/hip_runtime.h>
#include <hip/hip_fp16.h>

// SGConvolution: out = A @ (A @ x), A sparse COO (edge_row sorted).
// N=100000, E=1600000, D=64 (== wave width; lane d owns feature d).
//
// R3 -> R4:
//  - fp16 storage for the gathered feature table (halves gather lines and
//    past-L2 fetch; accumulation stays fp32; rounding ~0.1 << 0.67 thresh).
//  - Explicit double-buffered gather pipeline (CH=16, prefetch chunk k+1
//    while folding chunk k) with EPW=64 -> 25000 waves, VGPR kept low.
//  - Edge triples broadcast via readlane -> SGPR addressing + scalar
//    row-boundary branch (carried over from R3).

#define N_NODES 100000
#define N_EDGES 1600000
#define D_FEAT  64
#define EPW     64    // edges per wave; 1600000 / 64 = 25000 waves exactly
#define CH      16    // gather chunk (pipeline stage) size

__device__ __forceinline__ float readlane_f(float x, int j) {
    return __uint_as_float(__builtin_amdgcn_readlane(__float_as_uint(x), j));
}

__device__ __forceinline__ float to_f32(float x)  { return x; }
__device__ __forceinline__ float to_f32(__half x) { return __half2float(x); }

template <typename GT>
__global__ __launch_bounds__(256) void sg_spmm(
    const GT*    __restrict__ h,          // [N, 64] feature table (fp16 or fp32)
    const int*   __restrict__ erow,       // [E] sorted destination rows
    const int*   __restrict__ ecol,       // [E] source cols
    const float* __restrict__ eval,       // [E] edge weights
    float*       __restrict__ out)        // [N, 64] pre-zeroed fp32 output
{
    const int lane  = threadIdx.x & 63;
    const int wave  = (int)((blockIdx.x * blockDim.x + threadIdx.x) >> 6);
    const int start = wave * EPW;         // grid sized exactly; no tail

    // Coalesced preload of this wave's 64 edge triples (lane i = edge start+i).
    const int   r_v = erow[start + lane];
    const int   c_v = ecol[start + lane];
    const float w_v = eval[start + lane];

    GT gbuf[2][CH];

    // prefetch chunk 0
#pragma unroll
    for (int j = 0; j < CH; ++j) {
        const int c = __builtin_amdgcn_readlane(c_v, j);          // SGPR col
        gbuf[0][j] = h[(size_t)c * D_FEAT + lane];
    }

    int   cur_row = __builtin_amdgcn_readlane(r_v, 0);
    float acc     = 0.0f;

#pragma unroll
    for (int k = 0; k < EPW / CH; ++k) {
        if (k + 1 < EPW / CH) {
            // prefetch chunk k+1 while folding chunk k
#pragma unroll
            for (int j = 0; j < CH; ++j) {
                const int c = __builtin_amdgcn_readlane(c_v, (k + 1) * CH + j);
                gbuf[(k + 1) & 1][j] = h[(size_t)c * D_FEAT + lane];
            }
        }
#pragma unroll
        for (int j = 0; j < CH; ++j) {
            const int e = k * CH + j;
            const int r = __builtin_amdgcn_readlane(r_v, e);      // SGPR row
            if (r != cur_row) {                                   // scalar branch
                atomicAdd(&out[(size_t)cur_row * D_FEAT + lane], acc);
                acc = 0.0f;
                cur_row = r;
            }
            acc += readlane_f(w_v, e) * to_f32(gbuf[k & 1][j]);
        }
    }
    atomicAdd(&out[(size_t)cur_row * D_FEAT + lane], acc);
}

// float4 -> 4x fp16 cast, 4 elements per thread.
__global__ __launch_bounds__(256) void cast_f32_to_f16(
    const float* __restrict__ in, __half* __restrict__ out, int n4)
{
    const int i = blockIdx.x * blockDim.x + threadIdx.x;
    if (i >= n4) return;
    const float4 v = ((const float4*)in)[i];
    __half2 a = __floats2half2_rn(v.x, v.y);
    __half2 b = __floats2half2_rn(v.z, v.w);
    ((__half2*)out)[2 * i]     = a;
    ((__half2*)out)[2 * i + 1] = b;
}

extern "C" void kernel_launch(void* const* d_in, const int* in_sizes, int n_in,
                              void* d_out, int out_size, void* d_ws, size_t ws_size,
                              hipStream_t stream) {
    const float* x    = (const float*)d_in[0];
    const int*   erow = (const int*)  d_in[1];
    const int*   ecol = (const int*)  d_in[2];
    const float* eval = (const float*)d_in[3];
    float*       out  = (float*)d_out;

    const size_t n_elem     = (size_t)N_NODES * D_FEAT;      // 6.4e6
    const size_t f32_bytes  = n_elem * sizeof(float);        // 25.6 MB
    const size_t f16_bytes  = n_elem * sizeof(__half);       // 12.8 MB

    float*  h1f32 = (float*)d_ws;                            // [0, 25.6M)
    __half* h16   = (__half*)((char*)d_ws + f32_bytes);      // [25.6M, 38.4M)

    const int threads = 256;                                  // 4 waves/block
    const int spmm_blocks = (N_EDGES / EPW) * 64 / threads;   // 6250 exactly
    const int n4          = (int)(n_elem / 4);                // 1.6e6
    const int cast_blocks = (n4 + threads - 1) / threads;

    // ws and out are poisoned 0xAA before every timed call — zero fp32 accums.
    hipMemsetAsync(h1f32, 0, f32_bytes, stream);
    hipMemsetAsync(out,   0, f32_bytes, stream);

    if (ws_size >= f32_bytes + f16_bytes) {
        // fp16-gather path
        cast_f32_to_f16<<<cast_blocks, threads, 0, stream>>>(x, h16, n4);
        sg_spmm<__half><<<spmm_blocks, threads, 0, stream>>>(h16, erow, ecol, eval, h1f32);
        cast_f32_to_f16<<<cast_blocks, threads, 0, stream>>>(h1f32, h16, n4);
        // re-zero out is already done; spmm2 reads h16, flushes into out
        sg_spmm<__half><<<spmm_blocks, threads, 0, stream>>>(h16, erow, ecol, eval, out);
    } else {
        // fp32 fallback (ws only fits the intermediate)
        sg_spmm<float><<<spmm_blocks, threads, 0, stream>>>(x, erow, ecol, eval, h1f32);
        sg_spmm<float><<<spmm_blocks, threads, 0, stream>>>(h1f32, erow, ecol, eval, out);
    }
}